// Round 6
// baseline (500.329 us; speedup 1.0000x reference)
//
#include <hip/hip_runtime.h>

#define BATCH 4
#define NPTS  131072
#define KSEL  128
#define FDIM  96
#define QDIM  128

#define G   32                   // worker workgroups per batch
#define T   512                  // threads per workgroup
#define P   (NPTS / (G * T))     // 8 points per thread (registers)
#define NW  (T / 64)             // 8 waves per WG

#define AG __HIP_MEMORY_SCOPE_AGENT

// ---- workspace (255.1 KiB total, <= R3's proven 256 KiB budget) ----
// slots[BATCH][KSEL-1][G] u64 : FPS step winners (step s -> index s-1)
// fparts[BATCH][KSEL][G] u64  : feat argmax partials
// done u32 (128B padded)      : worker-completion counter for keepers
#define SLOTS_SZ  (BATCH * (KSEL - 1) * G * 8)   // 130048
#define FPART_SZ  (BATCH * KSEL * G * 8)         // 131072
#define FPART_OFF (SLOTS_SZ)
#define DONE_OFF  (SLOTS_SZ + FPART_SZ)
#define WS_TOTAL  (DONE_OFF + 128)

#define KEEPER_CAP 16384         // hard bound: ~1.7 ms of FMA, cannot hang

// d2 exactly as numpy: (dx*dx + dy*dy) + dz*dz, no FMA contraction
__device__ __forceinline__ float d2_np(float ax, float ay, float az,
                                       float bx, float by, float bz) {
    float dx = __fsub_rn(ax, bx);
    float dy = __fsub_rn(ay, by);
    float dz = __fsub_rn(az, bz);
    return __fadd_rn(__fadd_rn(__fmul_rn(dx, dx), __fmul_rn(dy, dy)),
                     __fmul_rn(dz, dz));
}

__device__ __forceinline__ unsigned long long pack_key(float v, unsigned n) {
    // max key == (max d2, then min index); d2 >= 0 so float bits are monotone.
    // key is never 0 for valid n (< NPTS), so 0 reliably means "unwritten".
    return ((unsigned long long)__float_as_uint(v) << 32) | (unsigned)(~n);
}

__global__ __launch_bounds__(T) void fps_kernel(
    const float* __restrict__ coords,          // [BATCH][NPTS][3]
    unsigned long long* __restrict__ slots,    // [BATCH][KSEL-1][G]
    unsigned long long* __restrict__ fparts,   // [BATCH][KSEL][G]
    unsigned int* __restrict__ done,
    float* __restrict__ out_sc)                // [BATCH][KSEL][3]
{
    const int blk = blockIdx.x;
    const int tid = threadIdx.x;

    if (blk >= BATCH * G) {
        // ---- clock keeper: double-bounded FMA spin (cap AND done flag) ----
        float a0 = tid * 1e-3f + 1.f, a1 = a0 + .1f, a2 = a0 + .2f, a3 = a0 + .3f;
        float a4 = a0 + .4f, a5 = a0 + .5f, a6 = a0 + .6f, a7 = a0 + .7f;
        for (int o = 0; o < KEEPER_CAP; ++o) {
            #pragma unroll
            for (int i = 0; i < 16; ++i) {
                a0 = __builtin_fmaf(a0, 1.0000001f, 1e-7f);
                a1 = __builtin_fmaf(a1, 1.0000001f, 1e-7f);
                a2 = __builtin_fmaf(a2, 1.0000001f, 1e-7f);
                a3 = __builtin_fmaf(a3, 1.0000001f, 1e-7f);
                a4 = __builtin_fmaf(a4, 1.0000001f, 1e-7f);
                a5 = __builtin_fmaf(a5, 1.0000001f, 1e-7f);
                a6 = __builtin_fmaf(a6, 1.0000001f, 1e-7f);
                a7 = __builtin_fmaf(a7, 1.0000001f, 1e-7f);
            }
            if ((o & 15) == 15 &&
                __hip_atomic_load(done, __ATOMIC_RELAXED, AG) >= BATCH * G)
                break;
        }
        asm volatile("" :: "v"(a0), "v"(a1), "v"(a2), "v"(a3),
                          "v"(a4), "v"(a5), "v"(a6), "v"(a7));
        return;
    }

    const int b    = blk / G;
    const int wgb  = blk % G;
    const int wid  = tid >> 6;
    const int lane = tid & 63;
    const float* cb = coords + (size_t)b * NPTS * 3;
    const int base = wgb * T + tid;            // stride G*T between my points

    // double-buffered per-wave partials: one barrier per step, race-free
    __shared__ unsigned long long s_md[2][NW];
    __shared__ unsigned long long s_ft[2][NW];

    float px[P], py[P], pz[P], md[P];
    #pragma unroll
    for (int j = 0; j < P; ++j) {
        int n = base + j * (G * T);
        px[j] = cb[n * 3 + 0];
        py[j] = cb[n * 3 + 1];
        pz[j] = cb[n * 3 + 2];
        md[j] = 1e10f;
    }

    float cx = cb[0], cy = cb[1], cz = cb[2];  // sample 0 = index 0
    if (tid == 0 && wgb == 0) {
        out_sc[((size_t)b * KSEL + 0) * 3 + 0] = cx;
        out_sc[((size_t)b * KSEL + 0) * 3 + 1] = cy;
        out_sc[((size_t)b * KSEL + 0) * 3 + 2] = cz;
    }

    for (int s = 1; s < KSEL; ++s) {
        const int pb = s & 1;
        // update md; track per-lane argmax of md (FPS) and of raw d2 (feat s-1)
        float bm = -1.0f; unsigned bn = 0;
        float bd = -1.0f; unsigned fn = 0;
        #pragma unroll
        for (int j = 0; j < P; ++j) {
            float d2 = d2_np(px[j], py[j], pz[j], cx, cy, cz);
            unsigned n = (unsigned)(base + j * (G * T));
            if (d2 > bd) { bd = d2; fn = n; }
            float m = fminf(md[j], d2);
            md[j] = m;
            if (m > bm) { bm = m; bn = n; }
        }
        unsigned long long kmd = pack_key(bm, bn);
        unsigned long long kft = pack_key(bd, fn);
        #pragma unroll
        for (int off = 32; off > 0; off >>= 1) {
            unsigned long long o1 = __shfl_xor(kmd, off, 64);
            unsigned long long o2 = __shfl_xor(kft, off, 64);
            if (o1 > kmd) kmd = o1;
            if (o2 > kft) kft = o2;
        }
        if (lane == 0) { s_md[pb][wid] = kmd; s_ft[pb][wid] = kft; }
        __syncthreads();                      // the ONLY barrier per step

        // wave 0 merges WG partials and publishes (slots first: critical path)
        if (wid == 0) {
            unsigned long long k1 = (lane < NW) ? s_md[pb][lane] : 0;
            unsigned long long k2 = (lane < NW) ? s_ft[pb][lane] : 0;
            #pragma unroll
            for (int off = 4; off > 0; off >>= 1) {
                unsigned long long o1 = __shfl_xor(k1, off, 64);
                unsigned long long o2 = __shfl_xor(k2, off, 64);
                if (o1 > k1) k1 = o1;
                if (o2 > k2) k2 = o2;
            }
            if (lane == 0) {
                __hip_atomic_store(
                    &slots[((size_t)b * (KSEL - 1) + (s - 1)) * G + wgb],
                    k1, __ATOMIC_RELAXED, AG);
                fparts[((size_t)b * KSEL + (s - 1)) * G + wgb] = k2;
            }
        }

        // ALL waves poll the 32 slots independently (proven R3 primitive),
        // then each computes the winner and fetches coords itself.
        unsigned long long k = 0;
        if (lane < G) {
            const unsigned long long* p =
                &slots[((size_t)b * (KSEL - 1) + (s - 1)) * G + lane];
            do {
                k = __hip_atomic_load(p, __ATOMIC_RELAXED, AG);
            } while (k == 0);
        }
        #pragma unroll
        for (int off = 32; off > 0; off >>= 1) {
            unsigned long long o = __shfl_xor(k, off, 64);
            if (o > k) k = o;
        }
        int idx = (int)(~(unsigned)(k & 0xFFFFFFFFull));
        cx = cb[idx * 3 + 0];                  // plain load, read-only data
        cy = cb[idx * 3 + 1];
        cz = cb[idx * 3 + 2];
        if (tid == 0 && wgb == 0) {
            out_sc[((size_t)b * KSEL + s) * 3 + 0] = cx;
            out_sc[((size_t)b * KSEL + s) * 3 + 1] = cy;
            out_sc[((size_t)b * KSEL + s) * 3 + 2] = cz;
        }
    }

    // feat partial for sample 127 (cx.. = sample 127 now)
    {
        float bd = -1.0f; unsigned fn = 0;
        #pragma unroll
        for (int j = 0; j < P; ++j) {
            float d2 = d2_np(px[j], py[j], pz[j], cx, cy, cz);
            unsigned n = (unsigned)(base + j * (G * T));
            if (d2 > bd) { bd = d2; fn = n; }
        }
        unsigned long long kft = pack_key(bd, fn);
        #pragma unroll
        for (int off = 32; off > 0; off >>= 1) {
            unsigned long long o = __shfl_xor(kft, off, 64);
            if (o > kft) kft = o;
        }
        if (lane == 0) s_ft[0][wid] = kft;
        __syncthreads();
        if (tid == 0) {
            unsigned long long k = s_ft[0][0];
            #pragma unroll
            for (int w = 1; w < NW; ++w)
                if (s_ft[0][w] > k) k = s_ft[0][w];
            fparts[((size_t)b * KSEL + (KSEL - 1)) * G + wgb] = k;
            __hip_atomic_fetch_add(done, 1u, __ATOMIC_RELAXED, AG);
        }
    }
}

__global__ __launch_bounds__(QDIM) void mlp_kernel(
    const float* __restrict__ features,   // [BATCH][NPTS][FDIM]
    const float* __restrict__ W1,         // [FDIM][QDIM]
    const float* __restrict__ b1,         // [QDIM]
    const float* __restrict__ W2,         // [QDIM][QDIM]
    const float* __restrict__ b2,         // [QDIM]
    const unsigned long long* __restrict__ fparts,  // [BATCH][KSEL][G]
    float* __restrict__ out_q)            // [BATCH][KSEL][QDIM]
{
    const int bk = blockIdx.x;            // b*KSEL + k
    const int b  = bk / KSEL;
    const int q  = threadIdx.x;
    const int lane = q & 63;

    __shared__ float fr[FDIM];
    __shared__ float h[QDIM];
    __shared__ int s_idx;

    if (q < 64) {
        unsigned long long k = 0;
        if (lane < G) k = fparts[(size_t)bk * G + lane];
        #pragma unroll
        for (int off = 32; off > 0; off >>= 1) {
            unsigned long long o = __shfl_xor(k, off, 64);
            if (o > k) k = o;
        }
        if (lane == 0) s_idx = (int)(~(unsigned)(k & 0xFFFFFFFFull));
    }
    __syncthreads();

    const float* frow = features + ((size_t)b * NPTS + s_idx) * FDIM;
    if (q < FDIM) fr[q] = frow[q];
    __syncthreads();

    float acc = b1[q];
    #pragma unroll 8
    for (int f = 0; f < FDIM; ++f) acc += fr[f] * W1[f * QDIM + q];
    h[q] = fmaxf(acc, 0.0f);
    __syncthreads();

    float acc2 = b2[q];
    #pragma unroll 8
    for (int j = 0; j < QDIM; ++j) acc2 += h[j] * W2[j * QDIM + q];
    out_q[(size_t)bk * QDIM + q] = acc2;
}

extern "C" void kernel_launch(void* const* d_in, const int* in_sizes, int n_in,
                              void* d_out, int out_size, void* d_ws, size_t ws_size,
                              hipStream_t stream) {
    (void)in_sizes; (void)n_in; (void)out_size; (void)ws_size;
    const float* coords   = (const float*)d_in[0];
    const float* features = (const float*)d_in[1];
    const float* W1       = (const float*)d_in[2];
    const float* b1       = (const float*)d_in[3];
    const float* W2       = (const float*)d_in[4];
    const float* b2       = (const float*)d_in[5];

    float* out_q  = (float*)d_out;
    float* out_sc = out_q + (size_t)BATCH * KSEL * QDIM;

    char* ws = (char*)d_ws;
    unsigned long long* slots  = (unsigned long long*)ws;
    unsigned long long* fparts = (unsigned long long*)(ws + FPART_OFF);
    unsigned int*       done   = (unsigned int*)(ws + DONE_OFF);

    hipMemsetAsync(d_ws, 0, WS_TOTAL, stream);
    fps_kernel<<<2 * BATCH * G, T, 0, stream>>>(coords, slots, fparts, done, out_sc);
    mlp_kernel<<<BATCH * KSEL, QDIM, 0, stream>>>(features, W1, b1, W2, b2,
                                                  fparts, out_q);
}

// Round 7
// 462.062 us; speedup vs baseline: 1.0828x; 1.0828x over previous
//
#include <hip/hip_runtime.h>

#define BATCH 4
#define NPTS  131072
#define KSEL  128
#define FDIM  96
#define QDIM  128

#define G   8                    // workgroups per batch (publishers per step)
#define T   1024                 // threads per workgroup
#define P   (NPTS / (G * T))     // 16 points per thread (registers)
#define NW  (T / 64)             // 16 waves per WG

#define AG __HIP_MEMORY_SCOPE_AGENT

// ---- workspace (~64 KiB) ----
// slots[BATCH][KSEL-1][G] u64 : one 64B line per (batch, step)
// fparts[BATCH][KSEL][G] u64  : feat argmax partials
#define SLOTS_SZ  (BATCH * (KSEL - 1) * G * 8)
#define FPART_SZ  (BATCH * KSEL * G * 8)
#define FPART_OFF (SLOTS_SZ)
#define WS_TOTAL  (SLOTS_SZ + FPART_SZ)

// d2 exactly as numpy: (dx*dx + dy*dy) + dz*dz, no FMA contraction
__device__ __forceinline__ float d2_np(float ax, float ay, float az,
                                       float bx, float by, float bz) {
    float dx = __fsub_rn(ax, bx);
    float dy = __fsub_rn(ay, by);
    float dz = __fsub_rn(az, bz);
    return __fadd_rn(__fadd_rn(__fmul_rn(dx, dx), __fmul_rn(dy, dy)),
                     __fmul_rn(dz, dz));
}

__device__ __forceinline__ unsigned long long pack_key(float v, unsigned n) {
    // (d2_bits << 32) | ~n : max == (max d2, then min index); never 0 for valid n
    return ((unsigned long long)__float_as_uint(v) << 32) | (unsigned)(~n);
}

__global__ __launch_bounds__(T) void fps_kernel(
    const float* __restrict__ coords,          // [BATCH][NPTS][3]
    unsigned long long* __restrict__ slots,    // [BATCH][KSEL-1][G]
    unsigned long long* __restrict__ fparts,   // [BATCH][KSEL][G]
    float* __restrict__ out_sc)                // [BATCH][KSEL][3]
{
    const int b    = blockIdx.x / G;
    const int wgb  = blockIdx.x % G;
    const int tid  = threadIdx.x;
    const int wid  = tid >> 6;
    const int lane = tid & 63;
    const float* cb = coords + (size_t)b * NPTS * 3;
    const int base = wgb * T + tid;            // stride G*T between my points

    __shared__ unsigned long long s_md[NW];
    __shared__ unsigned long long s_ft[NW];
    __shared__ float s_cur[3];

    float px[P], py[P], pz[P], md[P];
    #pragma unroll
    for (int j = 0; j < P; ++j) {
        int n = base + j * (G * T);
        px[j] = cb[n * 3 + 0];
        py[j] = cb[n * 3 + 1];
        pz[j] = cb[n * 3 + 2];
        md[j] = 1e10f;
    }

    float cx = cb[0], cy = cb[1], cz = cb[2];  // sample 0 = index 0
    if (tid == 0 && wgb == 0) {
        out_sc[((size_t)b * KSEL + 0) * 3 + 0] = cx;
        out_sc[((size_t)b * KSEL + 0) * 3 + 1] = cy;
        out_sc[((size_t)b * KSEL + 0) * 3 + 2] = cz;
    }

    for (int s = 1; s < KSEL; ++s) {
        // update md; per-lane argmax of md (FPS) and of raw d2 (feat for s-1)
        float bm = -1.0f; unsigned bn = 0;
        float bd = -1.0f; unsigned fn = 0;
        #pragma unroll
        for (int j = 0; j < P; ++j) {
            float d2 = d2_np(px[j], py[j], pz[j], cx, cy, cz);
            unsigned n = (unsigned)(base + j * (G * T));
            if (d2 > bd) { bd = d2; fn = n; }
            float m = fminf(md[j], d2);
            md[j] = m;
            if (m > bm) { bm = m; bn = n; }
        }
        unsigned long long kmd = pack_key(bm, bn);
        unsigned long long kft = pack_key(bd, fn);
        #pragma unroll
        for (int off = 32; off > 0; off >>= 1) {
            unsigned long long o1 = __shfl_xor(kmd, off, 64);
            unsigned long long o2 = __shfl_xor(kft, off, 64);
            if (o1 > kmd) kmd = o1;
            if (o2 > kft) kft = o2;
        }
        if (lane == 0) { s_md[wid] = kmd; s_ft[wid] = kft; }
        __syncthreads();                       // barrier 1: partials ready

        if (wid == 0) {
            // merge the 16 wave partials (lanes 0..15), publish, poll, resolve
            unsigned long long k1 = (lane < NW) ? s_md[lane] : 0;
            unsigned long long k2 = (lane < NW) ? s_ft[lane] : 0;
            #pragma unroll
            for (int off = 8; off > 0; off >>= 1) {
                unsigned long long o1 = __shfl_xor(k1, off, 64);
                unsigned long long o2 = __shfl_xor(k2, off, 64);
                if (o1 > k1) k1 = o1;
                if (o2 > k2) k2 = o2;
            }
            if (lane == 0) {
                __hip_atomic_store(
                    &slots[((size_t)b * (KSEL - 1) + (s - 1)) * G + wgb],
                    k1, __ATOMIC_RELAXED, AG);
                fparts[((size_t)b * KSEL + (s - 1)) * G + wgb] = k2;
            }
            // poll the single 64B slot line (lanes 0..7)
            unsigned long long k = 0;
            if (lane < G) {
                const unsigned long long* p =
                    &slots[((size_t)b * (KSEL - 1) + (s - 1)) * G + lane];
                do {
                    k = __hip_atomic_load(p, __ATOMIC_RELAXED, AG);
                } while (k == 0);
            }
            #pragma unroll
            for (int off = 4; off > 0; off >>= 1) {
                unsigned long long o = __shfl_xor(k, off, 64);
                if (o > k) k = o;
            }
            if (lane == 0) {
                int idx = (int)(~(unsigned)(k & 0xFFFFFFFFull));
                float wx = cb[idx * 3 + 0];    // plain cacheable load
                float wy = cb[idx * 3 + 1];
                float wz = cb[idx * 3 + 2];
                s_cur[0] = wx; s_cur[1] = wy; s_cur[2] = wz;
                if (wgb == 0) {
                    out_sc[((size_t)b * KSEL + s) * 3 + 0] = wx;
                    out_sc[((size_t)b * KSEL + s) * 3 + 1] = wy;
                    out_sc[((size_t)b * KSEL + s) * 3 + 2] = wz;
                }
            }
        }
        __syncthreads();                       // barrier 2: winner broadcast
        cx = s_cur[0]; cy = s_cur[1]; cz = s_cur[2];
    }

    // feat partial for sample 127 (cx.. = sample 127 now)
    {
        float bd = -1.0f; unsigned fn = 0;
        #pragma unroll
        for (int j = 0; j < P; ++j) {
            float d2 = d2_np(px[j], py[j], pz[j], cx, cy, cz);
            unsigned n = (unsigned)(base + j * (G * T));
            if (d2 > bd) { bd = d2; fn = n; }
        }
        unsigned long long kft = pack_key(bd, fn);
        #pragma unroll
        for (int off = 32; off > 0; off >>= 1) {
            unsigned long long o = __shfl_xor(kft, off, 64);
            if (o > kft) kft = o;
        }
        if (lane == 0) s_ft[wid] = kft;
        __syncthreads();
        if (tid == 0) {
            unsigned long long k = s_ft[0];
            #pragma unroll
            for (int w = 1; w < NW; ++w)
                if (s_ft[w] > k) k = s_ft[w];
            fparts[((size_t)b * KSEL + (KSEL - 1)) * G + wgb] = k;
        }
    }
}

__global__ __launch_bounds__(QDIM) void mlp_kernel(
    const float* __restrict__ features,   // [BATCH][NPTS][FDIM]
    const float* __restrict__ W1,         // [FDIM][QDIM]
    const float* __restrict__ b1,         // [QDIM]
    const float* __restrict__ W2,         // [QDIM][QDIM]
    const float* __restrict__ b2,         // [QDIM]
    const unsigned long long* __restrict__ fparts,  // [BATCH][KSEL][G]
    float* __restrict__ out_q)            // [BATCH][KSEL][QDIM]
{
    const int bk = blockIdx.x;            // b*KSEL + k
    const int b  = bk / KSEL;
    const int q  = threadIdx.x;
    const int lane = q & 63;

    __shared__ float fr[FDIM];
    __shared__ float h[QDIM];
    __shared__ int s_idx;

    if (q < 64) {
        unsigned long long k = 0;
        if (lane < G) k = fparts[(size_t)bk * G + lane];
        #pragma unroll
        for (int off = 4; off > 0; off >>= 1) {
            unsigned long long o = __shfl_xor(k, off, 64);
            if (o > k) k = o;
        }
        if (lane == 0) s_idx = (int)(~(unsigned)(k & 0xFFFFFFFFull));
    }
    __syncthreads();

    const float* frow = features + ((size_t)b * NPTS + s_idx) * FDIM;
    if (q < FDIM) fr[q] = frow[q];
    __syncthreads();

    float acc = b1[q];
    #pragma unroll 8
    for (int f = 0; f < FDIM; ++f) acc += fr[f] * W1[f * QDIM + q];
    h[q] = fmaxf(acc, 0.0f);
    __syncthreads();

    float acc2 = b2[q];
    #pragma unroll 8
    for (int j = 0; j < QDIM; ++j) acc2 += h[j] * W2[j * QDIM + q];
    out_q[(size_t)bk * QDIM + q] = acc2;
}

extern "C" void kernel_launch(void* const* d_in, const int* in_sizes, int n_in,
                              void* d_out, int out_size, void* d_ws, size_t ws_size,
                              hipStream_t stream) {
    (void)in_sizes; (void)n_in; (void)out_size; (void)ws_size;
    const float* coords   = (const float*)d_in[0];
    const float* features = (const float*)d_in[1];
    const float* W1       = (const float*)d_in[2];
    const float* b1       = (const float*)d_in[3];
    const float* W2       = (const float*)d_in[4];
    const float* b2       = (const float*)d_in[5];

    float* out_q  = (float*)d_out;
    float* out_sc = out_q + (size_t)BATCH * KSEL * QDIM;

    char* ws = (char*)d_ws;
    unsigned long long* slots  = (unsigned long long*)ws;
    unsigned long long* fparts = (unsigned long long*)(ws + FPART_OFF);

    hipMemsetAsync(d_ws, 0, WS_TOTAL, stream);
    fps_kernel<<<BATCH * G, T, 0, stream>>>(coords, slots, fparts, out_sc);
    mlp_kernel<<<BATCH * KSEL, QDIM, 0, stream>>>(features, W1, b1, W2, b2,
                                                  fparts, out_q);
}

// Round 8
// 457.157 us; speedup vs baseline: 1.0944x; 1.0107x over previous
//
#include <hip/hip_runtime.h>

#define BATCH 4
#define NPTS  131072
#define KSEL  128
#define FDIM  96
#define QDIM  128

#define G   32                   // workgroups per batch
#define T   512                  // threads per workgroup
#define P   (NPTS / (G * T))     // 8 points per thread (registers)
#define NW  (T / 64)             // 8 waves per WG

#define AG __HIP_MEMORY_SCOPE_AGENT

// ---- workspace (255 KiB, proven budget) ----
#define SLOTS_SZ  (BATCH * (KSEL - 1) * G * 8)   // 130048
#define FPART_SZ  (BATCH * KSEL * G * 8)         // 131072
#define FPART_OFF (SLOTS_SZ)
#define WS_TOTAL  (SLOTS_SZ + FPART_SZ)

// d2 exactly as numpy: (dx*dx + dy*dy) + dz*dz, no FMA contraction
__device__ __forceinline__ float d2_np(float ax, float ay, float az,
                                       float bx, float by, float bz) {
    float dx = __fsub_rn(ax, bx);
    float dy = __fsub_rn(ay, by);
    float dz = __fsub_rn(az, bz);
    return __fadd_rn(__fadd_rn(__fmul_rn(dx, dx), __fmul_rn(dy, dy)),
                     __fmul_rn(dz, dz));
}

__device__ __forceinline__ unsigned long long pack_key(float v, unsigned n) {
    // (d2_bits << 32) | ~n : max == (max d2, then min index); never 0 for valid n
    return ((unsigned long long)__float_as_uint(v) << 32) | (unsigned)(~n);
}

__global__ __launch_bounds__(T) void fps_kernel(
    const float* __restrict__ coords,          // [BATCH][NPTS][3]
    unsigned long long* __restrict__ slots,    // [BATCH][KSEL-1][G]
    unsigned long long* __restrict__ fparts,   // [BATCH][KSEL][G]
    float* __restrict__ out_sc)                // [BATCH][KSEL][3]
{
    const int b    = blockIdx.x / G;
    const int wgb  = blockIdx.x % G;
    const int tid  = threadIdx.x;
    const int wid  = tid >> 6;
    const int lane = tid & 63;
    const float* cb = coords + (size_t)b * NPTS * 3;
    const int base = wgb * T + tid;            // stride G*T between my points

    __shared__ unsigned long long s_md[NW];
    __shared__ unsigned long long s_ft[NW];
    __shared__ float s_samp[KSEL][3];          // winner coords per step
    volatile __shared__ int s_step;            // wave0 bumps when winner ready

    float px[P], py[P], pz[P], md[P];
    #pragma unroll
    for (int j = 0; j < P; ++j) {
        int n = base + j * (G * T);
        px[j] = cb[n * 3 + 0];
        py[j] = cb[n * 3 + 1];
        pz[j] = cb[n * 3 + 2];
        md[j] = 1e10f;
    }

    float cx = cb[0], cy = cb[1], cz = cb[2];  // sample 0 = index 0
    if (tid == 0) {
        s_samp[0][0] = cx; s_samp[0][1] = cy; s_samp[0][2] = cz;
        s_step = 0;
    }
    __syncthreads();

    for (int s = 1; s < KSEL; ++s) {
        // update md; per-lane argmax of md (FPS) and of raw d2 (feat for s-1)
        float bm = -1.0f; unsigned bn = 0;
        float bd = -1.0f; unsigned fn = 0;
        #pragma unroll
        for (int j = 0; j < P; ++j) {
            float d2 = d2_np(px[j], py[j], pz[j], cx, cy, cz);
            unsigned n = (unsigned)(base + j * (G * T));
            if (d2 > bd) { bd = d2; fn = n; }
            float m = fminf(md[j], d2);
            md[j] = m;
            if (m > bm) { bm = m; bn = n; }
        }
        unsigned long long kmd = pack_key(bm, bn);
        unsigned long long kft = pack_key(bd, fn);
        #pragma unroll
        for (int off = 32; off > 0; off >>= 1) {
            unsigned long long o1 = __shfl_xor(kmd, off, 64);
            unsigned long long o2 = __shfl_xor(kft, off, 64);
            if (o1 > kmd) kmd = o1;
            if (o2 > kft) kft = o2;
        }
        if (lane == 0) { s_md[wid] = kmd; s_ft[wid] = kft; }
        __syncthreads();                       // barrier 1: partials ready

        if (wid == 0) {
            // ---- critical path: merge, publish, poll, resolve ----
            unsigned long long k1 = (lane < NW) ? s_md[lane] : 0;
            #pragma unroll
            for (int off = 4; off > 0; off >>= 1) {
                unsigned long long o = __shfl_xor(k1, off, 64);
                if (o > k1) k1 = o;
            }
            if (lane == 0)
                __hip_atomic_store(
                    &slots[((size_t)b * (KSEL - 1) + (s - 1)) * G + wgb],
                    k1, __ATOMIC_RELAXED, AG);
            // poll all 32 slots (one lane each)
            unsigned long long k = 0;
            if (lane < G) {
                const unsigned long long* p =
                    &slots[((size_t)b * (KSEL - 1) + (s - 1)) * G + lane];
                do {
                    k = __hip_atomic_load(p, __ATOMIC_RELAXED, AG);
                } while (k == 0);
            }
            #pragma unroll
            for (int off = 32; off > 0; off >>= 1) {
                unsigned long long o = __shfl_xor(k, off, 64);
                if (o > k) k = o;
            }
            if (lane == 0) {
                int idx = (int)(~(unsigned)(k & 0xFFFFFFFFull));
                s_samp[s][0] = cb[idx * 3 + 0];   // plain cacheable loads
                s_samp[s][1] = cb[idx * 3 + 1];
                s_samp[s][2] = cb[idx * 3 + 2];
                __builtin_amdgcn_s_waitcnt(0);     // LDS writes visible
                s_step = s;                        // release burn waves
            }
        } else if (wid == 1) {
            // feat merge/store: off the critical path
            unsigned long long k2 = (lane < NW) ? s_ft[lane] : 0;
            #pragma unroll
            for (int off = 4; off > 0; off >>= 1) {
                unsigned long long o = __shfl_xor(k2, off, 64);
                if (o > k2) k2 = o;
            }
            if (lane == 0)
                fparts[((size_t)b * KSEL + (s - 1)) * G + wgb] = k2;
            // then burn-wait like the others
            float a0 = (float)lane + 1.f, a1 = a0 + .1f, a2 = a0 + .2f, a3 = a0 + .3f;
            while (s_step < s) {
                #pragma unroll
                for (int i = 0; i < 8; ++i) {
                    a0 = __builtin_fmaf(a0, 1.0000001f, 1e-7f);
                    a1 = __builtin_fmaf(a1, 1.0000001f, 1e-7f);
                    a2 = __builtin_fmaf(a2, 1.0000001f, 1e-7f);
                    a3 = __builtin_fmaf(a3, 1.0000001f, 1e-7f);
                }
            }
            asm volatile("" :: "v"(a0), "v"(a1), "v"(a2), "v"(a3));
        } else {
            // ---- adaptive clock burn: FMAs until wave0 posts the winner ----
            float a0 = (float)lane + 1.f, a1 = a0 + .1f, a2 = a0 + .2f, a3 = a0 + .3f;
            while (s_step < s) {
                #pragma unroll
                for (int i = 0; i < 8; ++i) {
                    a0 = __builtin_fmaf(a0, 1.0000001f, 1e-7f);
                    a1 = __builtin_fmaf(a1, 1.0000001f, 1e-7f);
                    a2 = __builtin_fmaf(a2, 1.0000001f, 1e-7f);
                    a3 = __builtin_fmaf(a3, 1.0000001f, 1e-7f);
                }
            }
            asm volatile("" :: "v"(a0), "v"(a1), "v"(a2), "v"(a3));
        }
        __syncthreads();                       // barrier 2: s_samp[s] visible
        cx = s_samp[s][0]; cy = s_samp[s][1]; cz = s_samp[s][2];
    }

    // feat partial for sample 127 (cx.. = sample 127 now)
    {
        float bd = -1.0f; unsigned fn = 0;
        #pragma unroll
        for (int j = 0; j < P; ++j) {
            float d2 = d2_np(px[j], py[j], pz[j], cx, cy, cz);
            unsigned n = (unsigned)(base + j * (G * T));
            if (d2 > bd) { bd = d2; fn = n; }
        }
        unsigned long long kft = pack_key(bd, fn);
        #pragma unroll
        for (int off = 32; off > 0; off >>= 1) {
            unsigned long long o = __shfl_xor(kft, off, 64);
            if (o > kft) kft = o;
        }
        if (lane == 0) s_ft[wid] = kft;
        __syncthreads();
        if (tid == 0) {
            unsigned long long k = s_ft[0];
            #pragma unroll
            for (int w = 1; w < NW; ++w)
                if (s_ft[w] > k) k = s_ft[w];
            fparts[((size_t)b * KSEL + (KSEL - 1)) * G + wgb] = k;
        }
    }

    // wg0 dumps all sampled coords (off critical path, once)
    if (wgb == 0 && tid < KSEL * 3) {
        const float* sf = &s_samp[0][0];
        out_sc[(size_t)b * KSEL * 3 + tid] = sf[tid];
    }
}

__global__ __launch_bounds__(QDIM) void mlp_kernel(
    const float* __restrict__ features,   // [BATCH][NPTS][FDIM]
    const float* __restrict__ W1,         // [FDIM][QDIM]
    const float* __restrict__ b1,         // [QDIM]
    const float* __restrict__ W2,         // [QDIM][QDIM]
    const float* __restrict__ b2,         // [QDIM]
    const unsigned long long* __restrict__ fparts,  // [BATCH][KSEL][G]
    float* __restrict__ out_q)            // [BATCH][KSEL][QDIM]
{
    const int bk = blockIdx.x;            // b*KSEL + k
    const int b  = bk / KSEL;
    const int q  = threadIdx.x;
    const int lane = q & 63;

    __shared__ float fr[FDIM];
    __shared__ float h[QDIM];
    __shared__ int s_idx;

    if (q < 64) {
        unsigned long long k = 0;
        if (lane < G) k = fparts[(size_t)bk * G + lane];
        #pragma unroll
        for (int off = 32; off > 0; off >>= 1) {
            unsigned long long o = __shfl_xor(k, off, 64);
            if (o > k) k = o;
        }
        if (lane == 0) s_idx = (int)(~(unsigned)(k & 0xFFFFFFFFull));
    }
    __syncthreads();

    const float* frow = features + ((size_t)b * NPTS + s_idx) * FDIM;
    if (q < FDIM) fr[q] = frow[q];
    __syncthreads();

    float acc = b1[q];
    #pragma unroll 8
    for (int f = 0; f < FDIM; ++f) acc += fr[f] * W1[f * QDIM + q];
    h[q] = fmaxf(acc, 0.0f);
    __syncthreads();

    float acc2 = b2[q];
    #pragma unroll 8
    for (int j = 0; j < QDIM; ++j) acc2 += h[j] * W2[j * QDIM + q];
    out_q[(size_t)bk * QDIM + q] = acc2;
}

extern "C" void kernel_launch(void* const* d_in, const int* in_sizes, int n_in,
                              void* d_out, int out_size, void* d_ws, size_t ws_size,
                              hipStream_t stream) {
    (void)in_sizes; (void)n_in; (void)out_size; (void)ws_size;
    const float* coords   = (const float*)d_in[0];
    const float* features = (const float*)d_in[1];
    const float* W1       = (const float*)d_in[2];
    const float* b1       = (const float*)d_in[3];
    const float* W2       = (const float*)d_in[4];
    const float* b2       = (const float*)d_in[5];

    float* out_q  = (float*)d_out;
    float* out_sc = out_q + (size_t)BATCH * KSEL * QDIM;

    char* ws = (char*)d_ws;
    unsigned long long* slots  = (unsigned long long*)ws;
    unsigned long long* fparts = (unsigned long long*)(ws + FPART_OFF);

    hipMemsetAsync(d_ws, 0, WS_TOTAL, stream);
    fps_kernel<<<BATCH * G, T, 0, stream>>>(coords, slots, fparts, out_sc);
    mlp_kernel<<<BATCH * KSEL, QDIM, 0, stream>>>(features, W1, b1, W2, b2,
                                                  fparts, out_q);
}